// Round 1
// baseline (1060.717 us; speedup 1.0000x reference)
//
#include <hip/hip_runtime.h>
#include <stdint.h>

// LSTM step: B=4096, IN=1024, H=4096. bf16-MFMA GEMMs with fp32 accumulate.
#define IN_ 1024
#define H_  4096
#define B_  4096
#define K_  5120   // IN_ + H_ (K-concat of x|hidden and Wx|Wh)

typedef short bf16x8 __attribute__((ext_vector_type(8)));
typedef float f32x4  __attribute__((ext_vector_type(4)));

__device__ __forceinline__ unsigned short f2bf(float x) {
    union { float f; uint32_t u; } v; v.f = x;
    return (unsigned short)((v.u + 0x7FFFu + ((v.u >> 16) & 1u)) >> 16);  // RNE
}
__device__ __forceinline__ float bf2f(uint32_t u16) {
    union { uint32_t u; float f; } v; v.u = u16 << 16; return v.f;
}

// Build bf16 [rows][5120] = concat(s1 [rows][1024], s2 [rows][4096]), RNE.
// grid*block must equal rows*K_/4 exactly (4096*1280 = 5,242,880).
__global__ __launch_bounds__(256) void cvt_cat(
    const float* __restrict__ s1, const float* __restrict__ s2,
    unsigned short* __restrict__ dst)
{
    int idx = blockIdx.x * 256 + threadIdx.x;       // one float4 per thread
    int r = idx / (K_ / 4);
    int c = (idx % (K_ / 4)) * 4;
    float4 v;
    if (c < IN_) v = *(const float4*)(s1 + (size_t)r * IN_ + c);
    else         v = *(const float4*)(s2 + (size_t)r * H_ + (c - IN_));
    ushort4 o = { f2bf(v.x), f2bf(v.y), f2bf(v.z), f2bf(v.w) };
    *(ushort4*)(dst + (size_t)r * K_ + c) = o;
}

// NT GEMM: P[m][n] = bf16( sum_k A[m][k]*W[n][k] + bias[n] )
// A [4096][5120] bf16, W [4096][5120] bf16, P [4096][4096] bf16.
// 128x128 tile, BK=64, 4 waves of 64x64, mfma_f32_16x16x32_bf16 (m97 structure).
__global__ __launch_bounds__(256) void gemm_gate(
    const unsigned short* __restrict__ A,
    const unsigned short* __restrict__ W,
    const float* __restrict__ bias,
    unsigned short* __restrict__ P)
{
    __shared__ __align__(16) unsigned short As[128 * 64];
    __shared__ __align__(16) unsigned short Bs[128 * 64];

    const int tid  = threadIdx.x;
    const int wid  = tid >> 6;
    const int lane = tid & 63;
    const int bm = (blockIdx.x & 31) * 128;   // m fastest: 32 consecutive blocks share W panel
    const int bn = (blockIdx.x >> 5) * 128;
    const int wm = (wid >> 1) * 64;
    const int wn = (wid & 1) * 64;

    f32x4 acc[4][4];
#pragma unroll
    for (int i = 0; i < 4; ++i)
#pragma unroll
        for (int j = 0; j < 4; ++j) acc[i][j] = (f32x4){0.f, 0.f, 0.f, 0.f};

    // staging geometry: 16 chunks of 1KB per tile; wave w owns chunks w*4..w*4+3
    const int ko_l  = (lane & 7) * 8;           // k offset (elements) this lane loads
    const int row_l = lane >> 3;                // row-within-chunk

    for (int k0 = 0; k0 < K_; k0 += 64) {
        __syncthreads();   // previous compute done before overwriting LDS
#pragma unroll
        for (int j = 0; j < 4; ++j) {
            const int chunk = wid * 4 + j;
            const int row   = chunk * 8 + row_l;
            const unsigned short* ga = A + (size_t)(bm + row) * K_ + k0 + ko_l;
            const unsigned short* gb = W + (size_t)(bn + row) * K_ + k0 + ko_l;
            __builtin_amdgcn_global_load_lds(
                (const __attribute__((address_space(1))) void*)ga,
                (__attribute__((address_space(3))) void*)&As[chunk * 512], 16, 0, 0);
            __builtin_amdgcn_global_load_lds(
                (const __attribute__((address_space(1))) void*)gb,
                (__attribute__((address_space(3))) void*)&Bs[chunk * 512], 16, 0, 0);
        }
        asm volatile("s_waitcnt vmcnt(0)" ::: "memory");
        __syncthreads();

#pragma unroll
        for (int kk = 0; kk < 64; kk += 32) {
            bf16x8 a[4], b[4];
#pragma unroll
            for (int mi = 0; mi < 4; ++mi)
                a[mi] = *(const bf16x8*)&As[(wm + mi * 16 + (lane & 15)) * 64 + kk + (lane >> 4) * 8];
#pragma unroll
            for (int ni = 0; ni < 4; ++ni)
                b[ni] = *(const bf16x8*)&Bs[(wn + ni * 16 + (lane & 15)) * 64 + kk + (lane >> 4) * 8];
#pragma unroll
            for (int mi = 0; mi < 4; ++mi)
#pragma unroll
                for (int ni = 0; ni < 4; ++ni)
                    acc[mi][ni] = __builtin_amdgcn_mfma_f32_16x16x32_bf16(
                        a[mi], b[ni], acc[mi][ni], 0, 0, 0);
        }
    }

    // epilogue: C/D layout col=lane&15, row=(lane>>4)*4+reg  [m89-verified]
#pragma unroll
    for (int ni = 0; ni < 4; ++ni) {
        const int col = bn + wn + ni * 16 + (lane & 15);
        const float bv = bias[col];
#pragma unroll
        for (int mi = 0; mi < 4; ++mi) {
            const int row0 = bm + wm + mi * 16 + (lane >> 4) * 4;
#pragma unroll
            for (int r = 0; r < 4; ++r)
                P[(size_t)(row0 + r) * H_ + col] = f2bf(acc[mi][ni][r] + bv);
        }
    }
}

// Fused gate elementwise + output GEMV. One block per batch row.
// y[b] = by + sum_h ( sigmoid(Po)*tanh( sigmoid(Pf)*cell + sigmoid(Pi)*tanh(Pc) ) * Wy[h] )
__global__ __launch_bounds__(256) void gates_gemv(
    const unsigned short* __restrict__ Pi, const unsigned short* __restrict__ Pf,
    const unsigned short* __restrict__ Po, const unsigned short* __restrict__ Pc,
    const float* __restrict__ cell, const float* __restrict__ Wy,
    const float* __restrict__ by, float* __restrict__ y)
{
    const int b = blockIdx.x;
    const int t = threadIdx.x;
    const size_t base = (size_t)b * H_;
    float part = 0.f;

#pragma unroll
    for (int j = 0; j < 4; ++j) {
        const int h = j * 1024 + t * 4;
        const uint2 ri = *(const uint2*)(Pi + base + h);
        const uint2 rf = *(const uint2*)(Pf + base + h);
        const uint2 ro = *(const uint2*)(Po + base + h);
        const uint2 rc = *(const uint2*)(Pc + base + h);
        const float4 cv = *(const float4*)(cell + base + h);
        const float4 wv = *(const float4*)(Wy + h);

        const uint32_t zi[4] = { ri.x & 0xffffu, ri.x >> 16, ri.y & 0xffffu, ri.y >> 16 };
        const uint32_t zf[4] = { rf.x & 0xffffu, rf.x >> 16, rf.y & 0xffffu, rf.y >> 16 };
        const uint32_t zo[4] = { ro.x & 0xffffu, ro.x >> 16, ro.y & 0xffffu, ro.y >> 16 };
        const uint32_t zc[4] = { rc.x & 0xffffu, rc.x >> 16, rc.y & 0xffffu, rc.y >> 16 };
        const float cc[4] = { cv.x, cv.y, cv.z, cv.w };
        const float ww[4] = { wv.x, wv.y, wv.z, wv.w };
#pragma unroll
        for (int e = 0; e < 4; ++e) {
            const float ig = 1.f / (1.f + __expf(-bf2f(zi[e])));
            const float fg = 1.f / (1.f + __expf(-bf2f(zf[e])));
            const float og = 1.f / (1.f + __expf(-bf2f(zo[e])));
            const float ct = tanhf(bf2f(zc[e]));
            const float cn = fg * cc[e] + ig * ct;
            const float hn = og * tanhf(cn);
            part += hn * ww[e];
        }
    }

    // block reduce (deterministic, no atomics)
#pragma unroll
    for (int off = 32; off > 0; off >>= 1) part += __shfl_down(part, off, 64);
    __shared__ float red[4];
    if ((t & 63) == 0) red[t >> 6] = part;
    __syncthreads();
    if (t == 0) y[b] = red[0] + red[1] + red[2] + red[3] + by[0];
}

extern "C" void kernel_launch(void* const* d_in, const int* in_sizes, int n_in,
                              void* d_out, int out_size, void* d_ws, size_t ws_size,
                              hipStream_t stream) {
    const float* x      = (const float*)d_in[0];
    const float* hidden = (const float*)d_in[1];
    const float* cell   = (const float*)d_in[2];
    const float* Wx[4]  = { (const float*)d_in[3], (const float*)d_in[4],
                            (const float*)d_in[5], (const float*)d_in[6] };
    const float* bx[4]  = { (const float*)d_in[7], (const float*)d_in[8],
                            (const float*)d_in[9], (const float*)d_in[10] };
    const float* Wh[4]  = { (const float*)d_in[11], (const float*)d_in[12],
                            (const float*)d_in[13], (const float*)d_in[14] };
    const float* Wy     = (const float*)d_in[15];
    const float* by     = (const float*)d_in[16];
    float* y = (float*)d_out;

    // ws layout (needs ~208 MiB):
    //   A  bf16 [4096][5120]  : 40 MiB
    //   Wb bf16 [4096][5120]  : 40 MiB (reused per gate; stream-serialized)
    //   P  bf16 [4][4096][4096]: 128 MiB
    unsigned short* Ab = (unsigned short*)d_ws;
    unsigned short* Wb = Ab + (size_t)B_ * K_;
    unsigned short* Pg[4];
    {
        unsigned short* p0 = Wb + (size_t)H_ * K_;
        for (int g = 0; g < 4; ++g) Pg[g] = p0 + (size_t)g * B_ * H_;
    }

    const int cvt_grid = (B_ * (K_ / 4)) / 256;   // 20480, exact
    cvt_cat<<<cvt_grid, 256, 0, stream>>>(x, hidden, Ab);

    for (int g = 0; g < 4; ++g) {
        cvt_cat<<<cvt_grid, 256, 0, stream>>>(Wx[g], Wh[g], Wb);
        gemm_gate<<<(B_ / 128) * (H_ / 128), 256, 0, stream>>>(Ab, Wb, bx[g], Pg[g]);
    }

    gates_gemv<<<B_, 256, 0, stream>>>(Pg[0], Pg[1], Pg[2], Pg[3], cell, Wy, by, y);
}

// Round 2
// 791.795 us; speedup vs baseline: 1.3396x; 1.3396x over previous
//
#include <hip/hip_runtime.h>
#include <stdint.h>

// LSTM step: B=4096, IN=1024, H=4096. bf16-MFMA GEMMs with fp32 accumulate.
// GEMM = 256x256 tile, BK=64, 8 waves, 4-phase/K-tile pipeline with counted
// vmcnt (T3+T4), LDS XOR-swizzle (T2), setprio (T5), XCD swizzle (T1).
#define IN_ 1024
#define H_  4096
#define B_  4096
#define K_  5120   // IN_ + H_ (K-concat of x|hidden and Wx|Wh)
#define NT_ 80     // K_ / 64 K-tiles

typedef short bf16x8 __attribute__((ext_vector_type(8)));
typedef float f32x4  __attribute__((ext_vector_type(4)));

__device__ __forceinline__ unsigned short f2bf(float x) {
    union { float f; uint32_t u; } v; v.f = x;
    return (unsigned short)((v.u + 0x7FFFu + ((v.u >> 16) & 1u)) >> 16);  // RNE
}
__device__ __forceinline__ float bf2f(uint32_t u16) {
    union { uint32_t u; float f; } v; v.u = u16 << 16; return v.f;
}

// Build bf16 [rows][5120] = concat(s1 [rows][1024], s2 [rows][4096]), RNE.
__global__ __launch_bounds__(256) void cvt_cat(
    const float* __restrict__ s1, const float* __restrict__ s2,
    unsigned short* __restrict__ dst)
{
    int idx = blockIdx.x * 256 + threadIdx.x;       // one float4 per thread
    int r = idx / (K_ / 4);
    int c = (idx % (K_ / 4)) * 4;
    float4 v;
    if (c < IN_) v = *(const float4*)(s1 + (size_t)r * IN_ + c);
    else         v = *(const float4*)(s2 + (size_t)r * H_ + (c - IN_));
    ushort4 o = { f2bf(v.x), f2bf(v.y), f2bf(v.z), f2bf(v.w) };
    *(ushort4*)(dst + (size_t)r * K_ + c) = o;
}

// LDS swizzle: within a [256][32]-bf16 sub-tile (64 B rows), XOR byte-col
// bits 4-5 with row bits 1-2. 8 consecutive rows -> 8 distinct 16B slots
// covering all 32 banks. Involution; 16B-granular (global_load_lds safe).
__device__ __forceinline__ int swz(int row) { return ((row >> 1) & 3) << 4; }

// NT GEMM: P[m][n] = bf16( sum_k A[m][k]*W[n][k] + bias[n] )
// A [4096][5120] bf16, W [4096][5120] bf16, P [4096][4096] bf16.
__global__ __launch_bounds__(512, 2) void gemm_gate8(
    const unsigned short* __restrict__ A,
    const unsigned short* __restrict__ W,
    const float* __restrict__ bias,
    unsigned short* __restrict__ P)
{
    // 128 KiB: buf(2) x { A_k0 | A_k1 | B_k0 | B_k1 }, each [256][32] bf16 (16 KiB)
    __shared__ __align__(16) char ldsb[131072];

    const int tid  = threadIdx.x;
    const int wid  = tid >> 6;
    const int lane = tid & 63;

    // XCD-bijective block swizzle: 256 blocks, 8 XCDs, 32 blocks/XCD chunk.
    // Within a chunk m is fastest -> 16 consecutive blocks share the W panel.
    const int wg = (blockIdx.x & 7) * 32 + (blockIdx.x >> 3);
    const int mt = wg & 15, nt = wg >> 4;
    const int bm = mt * 256, bn = nt * 256;

    const int wm = wid >> 2;   // 0..1 -> wave M-half (128 rows)
    const int wn = wid & 3;    // 0..3 -> wave N-quarter (64 cols)

    const int l15 = lane & 15;
    const int c0  = (lane >> 4) << 4;   // fragment k-slot byte offset (0/16/32/48)

    // staging coords: thread owns 16B slots q0 = wid*64+lane and q0+512 of each
    // 16 KiB half-tile chunk; LDS write is linear, so the global SOURCE column
    // is pre-swizzled (inverse of the read swizzle).
    const int q0  = wid * 64 + lane;
    const int r0  = q0 >> 2;                       // row 0..127
    const int cb0 = ((q0 & 3) << 4) ^ swz(r0);     // logical col byte
    const int r1  = r0 + 128;                      // row 128..255 (slot q0+512)
    const int cb1 = ((q0 & 3) << 4) ^ swz(r1);

    f32x4 acc[8][4];
#pragma unroll
    for (int i = 0; i < 8; ++i)
#pragma unroll
        for (int j = 0; j < 4; ++j) acc[i][j] = (f32x4){0.f, 0.f, 0.f, 0.f};

    // stage one half-tile (2 x global_load_lds width-16 per thread)
    auto stage = [&](int isB, int ksel, int tau) {
        if (tau >= NT_) tau -= 2;  // tail clamp: re-stage same-parity tile (identical bytes)
        const int kbase = tau * 64 + ksel * 32;
        const int chunk = (tau & 1) * 65536 + isB * 32768 + ksel * 16384;
        const unsigned short* src = isB ? W : A;
        const int gb = isB ? bn : bm;
        __builtin_amdgcn_global_load_lds(
            (const __attribute__((address_space(1))) void*)(src + (size_t)(gb + r0) * K_ + kbase + (cb0 >> 1)),
            (__attribute__((address_space(3))) void*)(ldsb + chunk + wid * 1024), 16, 0, 0);
        __builtin_amdgcn_global_load_lds(
            (const __attribute__((address_space(1))) void*)(src + (size_t)(gb + r1) * K_ + kbase + (cb1 >> 1)),
            (__attribute__((address_space(3))) void*)(ldsb + chunk + 8192 + wid * 1024), 16, 0, 0);
    };

    // prologue: half-tile slots s=0..5  (tile0 all 4 kinds + tile1 k-lo pair)
    stage(0, 0, 0); stage(1, 0, 0); stage(0, 1, 0);
    stage(1, 1, 0); stage(0, 0, 1); stage(1, 0, 1);
    asm volatile("s_waitcnt vmcnt(8)" ::: "memory");  // s=0,1 (tile0 k-lo) landed
    __builtin_amdgcn_s_barrier();

    for (int T = 0; T < NT_; ++T) {
        const char* base = ldsb + (T & 1) * 65536;
#pragma unroll
        for (int p = 0; p < 4; ++p) {
            const int ks = p >> 1;   // k-step (0: k 0..31, 1: k 32..63)
            const int mh = p & 1;    // wave-tile m-half (64 rows)
            const char* Ab = base + ks * 16384;
            const char* Bb = base + 32768 + ks * 16384;

            bf16x8 a[4], b[4];
#pragma unroll
            for (int mi = 0; mi < 4; ++mi) {
                const int row = wm * 128 + mh * 64 + mi * 16 + l15;
                a[mi] = *(const bf16x8*)(Ab + row * 64 + (c0 ^ swz(row)));
            }
#pragma unroll
            for (int ni = 0; ni < 4; ++ni) {
                const int row = wn * 64 + ni * 16 + l15;
                b[ni] = *(const bf16x8*)(Bb + row * 64 + (c0 ^ swz(row)));
            }

            // stage half-tile s = 4T + p + 6 (6-slot lead; k0 chunks of tile T
            // die after phase 1, so overwriting them from phase 2 on is safe)
            if      (p == 0) stage(0, 1, T + 1);   // A_k1 of T+1
            else if (p == 1) stage(1, 1, T + 1);   // B_k1 of T+1
            else if (p == 2) stage(0, 0, T + 2);   // A_k0 of T+2
            else             stage(1, 0, T + 2);   // B_k0 of T+2

            // counted wait (never 0): newest 4 half-tiles may stay in flight
            if (p & 1) asm volatile("s_waitcnt vmcnt(8)" ::: "memory");
            __builtin_amdgcn_s_barrier();
            asm volatile("s_waitcnt lgkmcnt(0)" ::: "memory");
            __builtin_amdgcn_sched_barrier(0);     // rule #18: pin MFMA below the wait
            __builtin_amdgcn_s_setprio(1);
#pragma unroll
            for (int mi = 0; mi < 4; ++mi)
#pragma unroll
                for (int ni = 0; ni < 4; ++ni)
                    acc[mh * 4 + mi][ni] = __builtin_amdgcn_mfma_f32_16x16x32_bf16(
                        a[mi], b[ni], acc[mh * 4 + mi][ni], 0, 0, 0);
            __builtin_amdgcn_s_setprio(0);
            __builtin_amdgcn_s_barrier();
        }
    }

    // epilogue: C/D layout col=lane&15, row=(lane>>4)*4+reg  [m89-verified]
#pragma unroll
    for (int ni = 0; ni < 4; ++ni) {
        const int col = bn + wn * 64 + ni * 16 + l15;
        const float bv = bias[col];
#pragma unroll
        for (int ai = 0; ai < 8; ++ai) {
            const int row0 = bm + wm * 128 + (ai >> 2) * 64 + (ai & 3) * 16 + (lane >> 4) * 4;
#pragma unroll
            for (int r = 0; r < 4; ++r)
                P[(size_t)(row0 + r) * H_ + col] = f2bf(acc[ai][ni][r] + bv);
        }
    }
}

// Fused gate elementwise + output GEMV. One block per batch row.
__global__ __launch_bounds__(256) void gates_gemv(
    const unsigned short* __restrict__ Pi, const unsigned short* __restrict__ Pf,
    const unsigned short* __restrict__ Po, const unsigned short* __restrict__ Pc,
    const float* __restrict__ cell, const float* __restrict__ Wy,
    const float* __restrict__ by, float* __restrict__ y)
{
    const int b = blockIdx.x;
    const int t = threadIdx.x;
    const size_t base = (size_t)b * H_;
    float part = 0.f;

#pragma unroll
    for (int j = 0; j < 4; ++j) {
        const int h = j * 1024 + t * 4;
        const uint2 ri = *(const uint2*)(Pi + base + h);
        const uint2 rf = *(const uint2*)(Pf + base + h);
        const uint2 ro = *(const uint2*)(Po + base + h);
        const uint2 rc = *(const uint2*)(Pc + base + h);
        const float4 cv = *(const float4*)(cell + base + h);
        const float4 wv = *(const float4*)(Wy + h);

        const uint32_t zi[4] = { ri.x & 0xffffu, ri.x >> 16, ri.y & 0xffffu, ri.y >> 16 };
        const uint32_t zf[4] = { rf.x & 0xffffu, rf.x >> 16, rf.y & 0xffffu, rf.y >> 16 };
        const uint32_t zo[4] = { ro.x & 0xffffu, ro.x >> 16, ro.y & 0xffffu, ro.y >> 16 };
        const uint32_t zc[4] = { rc.x & 0xffffu, rc.x >> 16, rc.y & 0xffffu, rc.y >> 16 };
        const float cc[4] = { cv.x, cv.y, cv.z, cv.w };
        const float ww[4] = { wv.x, wv.y, wv.z, wv.w };
#pragma unroll
        for (int e = 0; e < 4; ++e) {
            const float ig = 1.f / (1.f + __expf(-bf2f(zi[e])));
            const float fg = 1.f / (1.f + __expf(-bf2f(zf[e])));
            const float og = 1.f / (1.f + __expf(-bf2f(zo[e])));
            const float ct = tanhf(bf2f(zc[e]));
            const float cn = fg * cc[e] + ig * ct;
            const float hn = og * tanhf(cn);
            part += hn * ww[e];
        }
    }

    // block reduce (deterministic, no atomics)
#pragma unroll
    for (int off = 32; off > 0; off >>= 1) part += __shfl_down(part, off, 64);
    __shared__ float red[4];
    if ((t & 63) == 0) red[t >> 6] = part;
    __syncthreads();
    if (t == 0) y[b] = red[0] + red[1] + red[2] + red[3] + by[0];
}

extern "C" void kernel_launch(void* const* d_in, const int* in_sizes, int n_in,
                              void* d_out, int out_size, void* d_ws, size_t ws_size,
                              hipStream_t stream) {
    const float* x      = (const float*)d_in[0];
    const float* hidden = (const float*)d_in[1];
    const float* cell   = (const float*)d_in[2];
    const float* Wx[4]  = { (const float*)d_in[3], (const float*)d_in[4],
                            (const float*)d_in[5], (const float*)d_in[6] };
    const float* bx[4]  = { (const float*)d_in[7], (const float*)d_in[8],
                            (const float*)d_in[9], (const float*)d_in[10] };
    const float* Wh[4]  = { (const float*)d_in[11], (const float*)d_in[12],
                            (const float*)d_in[13], (const float*)d_in[14] };
    const float* Wy     = (const float*)d_in[15];
    const float* by     = (const float*)d_in[16];
    float* y = (float*)d_out;

    // ws layout (~208 MiB):
    //   A  bf16 [4096][5120]   : 40 MiB
    //   Wb bf16 [4096][5120]   : 40 MiB (reused per gate; stream-serialized)
    //   P  bf16 [4][4096][4096]: 128 MiB
    unsigned short* Ab = (unsigned short*)d_ws;
    unsigned short* Wb = Ab + (size_t)B_ * K_;
    unsigned short* Pg[4];
    {
        unsigned short* p0 = Wb + (size_t)H_ * K_;
        for (int g = 0; g < 4; ++g) Pg[g] = p0 + (size_t)g * B_ * H_;
    }

    const int cvt_grid = (B_ * (K_ / 4)) / 256;   // 20480, exact
    cvt_cat<<<cvt_grid, 256, 0, stream>>>(x, hidden, Ab);

    for (int g = 0; g < 4; ++g) {
        cvt_cat<<<cvt_grid, 256, 0, stream>>>(Wx[g], Wh[g], Wb);
        gemm_gate8<<<256, 512, 0, stream>>>(Ab, Wb, bx[g], Pg[g]);
    }

    gates_gemv<<<B_, 256, 0, stream>>>(Pg[0], Pg[1], Pg[2], Pg[3], cell, Wy, by, y);
}

// Round 3
// 764.685 us; speedup vs baseline: 1.3871x; 1.0355x over previous
//
#include <hip/hip_runtime.h>
#include <stdint.h>

// LSTM step: B=4096, IN=1024, H=4096. bf16-MFMA GEMMs with fp32 accumulate.
// GEMM = 256x256 tile, BK=64, 8 waves, 2-phase/K-tile pipeline (12 ds_read +
// 32 MFMA per phase = 0.375 reads/MFMA), counted vmcnt (T3+T4), LDS
// XOR-swizzle (T2), setprio (T5), XCD-bijective block swizzle (T1).
#define IN_ 1024
#define H_  4096
#define B_  4096
#define K_  5120   // IN_ + H_ (K-concat of x|hidden and Wx|Wh)
#define NT_ 80     // K_ / 64 K-tiles

typedef short bf16x8 __attribute__((ext_vector_type(8)));
typedef float f32x4  __attribute__((ext_vector_type(4)));

__device__ __forceinline__ unsigned short f2bf(float x) {
    union { float f; uint32_t u; } v; v.f = x;
    return (unsigned short)((v.u + 0x7FFFu + ((v.u >> 16) & 1u)) >> 16);  // RNE
}
__device__ __forceinline__ float bf2f(uint32_t u16) {
    union { uint32_t u; float f; } v; v.u = u16 << 16; return v.f;
}

// Build bf16 [rows][5120] = concat(s1 [rows][1024], s2 [rows][4096]), RNE.
__global__ __launch_bounds__(256) void cvt_cat(
    const float* __restrict__ s1, const float* __restrict__ s2,
    unsigned short* __restrict__ dst)
{
    int idx = blockIdx.x * 256 + threadIdx.x;       // one float4 per thread
    int r = idx / (K_ / 4);
    int c = (idx % (K_ / 4)) * 4;
    float4 v;
    if (c < IN_) v = *(const float4*)(s1 + (size_t)r * IN_ + c);
    else         v = *(const float4*)(s2 + (size_t)r * H_ + (c - IN_));
    ushort4 o = { f2bf(v.x), f2bf(v.y), f2bf(v.z), f2bf(v.w) };
    *(ushort4*)(dst + (size_t)r * K_ + c) = o;
}

// LDS swizzle: within a [256][32]-bf16 sub-tile (64 B rows), XOR byte-col
// bits 4-5 with row bits 1-2. 8 consecutive rows -> 8 distinct 16B slots
// covering all 32 banks. Involution; 16B-granular (global_load_lds safe).
__device__ __forceinline__ int swz(int row) { return ((row >> 1) & 3) << 4; }

// NT GEMM: P[m][n] = bf16( sum_k A[m][k]*W[n][k] + bias[n] )
// A [4096][5120] bf16, W [4096][5120] bf16, P [4096][4096] bf16.
__global__ __launch_bounds__(512, 2) void gemm_gate8(
    const unsigned short* __restrict__ A,
    const unsigned short* __restrict__ W,
    const float* __restrict__ bias,
    unsigned short* __restrict__ P)
{
    // 128 KiB: buf(2) x { A_k0 | A_k1 | B_k0 | B_k1 }, each [256][32] bf16 (16 KiB)
    __shared__ __align__(16) char ldsb[131072];

    const int tid  = threadIdx.x;
    const int wid  = tid >> 6;
    const int lane = tid & 63;

    // XCD-bijective block swizzle: 256 blocks, 8 XCDs, 32 blocks/XCD chunk.
    // Within a chunk m is fastest -> 16 consecutive blocks share the W panel.
    const int wg = (blockIdx.x & 7) * 32 + (blockIdx.x >> 3);
    const int mt = wg & 15, nt = wg >> 4;
    const int bm = mt * 256, bn = nt * 256;

    const int wm = wid >> 2;   // 0..1 -> wave M-half (128 rows)
    const int wn = wid & 3;    // 0..3 -> wave N-quarter (64 cols)

    const int l15 = lane & 15;
    const int c0  = (lane >> 4) << 4;   // fragment k-slot byte offset (0/16/32/48)

    // staging coords: thread owns 16B slots q0 = wid*64+lane and q0+512 of each
    // 16 KiB half-tile chunk; LDS write is linear, so the global SOURCE column
    // is pre-swizzled (inverse of the read swizzle).
    const int q0  = wid * 64 + lane;
    const int r0  = q0 >> 2;                       // row 0..127
    const int cb0 = ((q0 & 3) << 4) ^ swz(r0);     // logical col byte
    const int r1  = r0 + 128;                      // row 128..255 (slot q0+512)
    const int cb1 = ((q0 & 3) << 4) ^ swz(r1);

    f32x4 acc[8][4];
#pragma unroll
    for (int i = 0; i < 8; ++i)
#pragma unroll
        for (int j = 0; j < 4; ++j) acc[i][j] = (f32x4){0.f, 0.f, 0.f, 0.f};

    // stage one half-tile (2 x global_load_lds width-16 per thread)
    auto stage = [&](int isB, int ksel, int tau) {
        if (tau >= NT_) tau -= 2;  // tail clamp: re-stage same-parity tile (identical bytes)
        const int kbase = tau * 64 + ksel * 32;
        const int chunk = (tau & 1) * 65536 + isB * 32768 + ksel * 16384;
        const unsigned short* src = isB ? W : A;
        const int gb = isB ? bn : bm;
        __builtin_amdgcn_global_load_lds(
            (const __attribute__((address_space(1))) void*)(src + (size_t)(gb + r0) * K_ + kbase + (cb0 >> 1)),
            (__attribute__((address_space(3))) void*)(ldsb + chunk + wid * 1024), 16, 0, 0);
        __builtin_amdgcn_global_load_lds(
            (const __attribute__((address_space(1))) void*)(src + (size_t)(gb + r1) * K_ + kbase + (cb1 >> 1)),
            (__attribute__((address_space(3))) void*)(ldsb + chunk + 8192 + wid * 1024), 16, 0, 0);
    };

    // prologue half-tile pairs: s0={A,B}_k0(0), s1={A,B}_k1(0), s2={A,B}_k0(1)
    stage(0, 0, 0); stage(1, 0, 0);
    stage(0, 1, 0); stage(1, 1, 0);
    stage(0, 0, 1); stage(1, 0, 1);
    asm volatile("s_waitcnt vmcnt(8)" ::: "memory");  // s0 landed
    __builtin_amdgcn_s_barrier();

    for (int T = 0; T < NT_; ++T) {
        const char* base = ldsb + (T & 1) * 65536;
#pragma unroll
        for (int p = 0; p < 2; ++p) {   // p == ks (k-half: 0 -> k 0..31, 1 -> k 32..63)
            const char* Ab = base + p * 16384;
            const char* Bb = base + 32768 + p * 16384;

            // 12 ds_read_b128: every fragment read exactly once per K-tile
            bf16x8 a[8], b[4];
#pragma unroll
            for (int mi = 0; mi < 8; ++mi) {
                const int row = wm * 128 + mi * 16 + l15;
                a[mi] = *(const bf16x8*)(Ab + row * 64 + (c0 ^ swz(row)));
            }
#pragma unroll
            for (int ni = 0; ni < 4; ++ni) {
                const int row = wn * 64 + ni * 16 + l15;
                b[ni] = *(const bf16x8*)(Bb + row * 64 + (c0 ^ swz(row)));
            }

            // stage 2 half-tiles (4 loads/thread):
            //   p==0 -> {A,B}_k1 of T+1;  p==1 -> {A,B}_k0 of T+2
            if (p == 0) { stage(0, 1, T + 1); stage(1, 1, T + 1); }
            else        { stage(0, 0, T + 2); stage(1, 0, T + 2); }

            // counted wait (never 0): newest 8 loads (this phase + previous
            // phase) stay in flight; phase X-2's pair — exactly what the next
            // phase reads — is guaranteed landed.
            asm volatile("s_waitcnt vmcnt(8)" ::: "memory");
            __builtin_amdgcn_s_barrier();
            asm volatile("s_waitcnt lgkmcnt(0)" ::: "memory");
            __builtin_amdgcn_sched_barrier(0);     // rule #18: pin MFMA below the wait
            __builtin_amdgcn_s_setprio(1);
#pragma unroll
            for (int mi = 0; mi < 8; ++mi)
#pragma unroll
                for (int ni = 0; ni < 4; ++ni)
                    acc[mi][ni] = __builtin_amdgcn_mfma_f32_16x16x32_bf16(
                        a[mi], b[ni], acc[mi][ni], 0, 0, 0);
            __builtin_amdgcn_s_setprio(0);
            __builtin_amdgcn_s_barrier();
        }
    }

    // epilogue: C/D layout col=lane&15, row=(lane>>4)*4+reg  [m89-verified]
#pragma unroll
    for (int ni = 0; ni < 4; ++ni) {
        const int col = bn + wn * 64 + ni * 16 + l15;
        const float bv = bias[col];
#pragma unroll
        for (int mi = 0; mi < 8; ++mi) {
            const int row0 = bm + wm * 128 + mi * 16 + (lane >> 4) * 4;
#pragma unroll
            for (int r = 0; r < 4; ++r)
                P[(size_t)(row0 + r) * H_ + col] = f2bf(acc[mi][ni][r] + bv);
        }
    }
}

// Fused gate elementwise + output GEMV. One block per batch row.
__global__ __launch_bounds__(256) void gates_gemv(
    const unsigned short* __restrict__ Pi, const unsigned short* __restrict__ Pf,
    const unsigned short* __restrict__ Po, const unsigned short* __restrict__ Pc,
    const float* __restrict__ cell, const float* __restrict__ Wy,
    const float* __restrict__ by, float* __restrict__ y)
{
    const int b = blockIdx.x;
    const int t = threadIdx.x;
    const size_t base = (size_t)b * H_;
    float part = 0.f;

#pragma unroll
    for (int j = 0; j < 4; ++j) {
        const int h = j * 1024 + t * 4;
        const uint2 ri = *(const uint2*)(Pi + base + h);
        const uint2 rf = *(const uint2*)(Pf + base + h);
        const uint2 ro = *(const uint2*)(Po + base + h);
        const uint2 rc = *(const uint2*)(Pc + base + h);
        const float4 cv = *(const float4*)(cell + base + h);
        const float4 wv = *(const float4*)(Wy + h);

        const uint32_t zi[4] = { ri.x & 0xffffu, ri.x >> 16, ri.y & 0xffffu, ri.y >> 16 };
        const uint32_t zf[4] = { rf.x & 0xffffu, rf.x >> 16, rf.y & 0xffffu, rf.y >> 16 };
        const uint32_t zo[4] = { ro.x & 0xffffu, ro.x >> 16, ro.y & 0xffffu, ro.y >> 16 };
        const uint32_t zc[4] = { rc.x & 0xffffu, rc.x >> 16, rc.y & 0xffffu, rc.y >> 16 };
        const float cc[4] = { cv.x, cv.y, cv.z, cv.w };
        const float ww[4] = { wv.x, wv.y, wv.z, wv.w };
#pragma unroll
        for (int e = 0; e < 4; ++e) {
            const float ig = 1.f / (1.f + __expf(-bf2f(zi[e])));
            const float fg = 1.f / (1.f + __expf(-bf2f(zf[e])));
            const float og = 1.f / (1.f + __expf(-bf2f(zo[e])));
            const float ct = tanhf(bf2f(zc[e]));
            const float cn = fg * cc[e] + ig * ct;
            const float hn = og * tanhf(cn);
            part += hn * ww[e];
        }
    }

    // block reduce (deterministic, no atomics)
#pragma unroll
    for (int off = 32; off > 0; off >>= 1) part += __shfl_down(part, off, 64);
    __shared__ float red[4];
    if ((t & 63) == 0) red[t >> 6] = part;
    __syncthreads();
    if (t == 0) y[b] = red[0] + red[1] + red[2] + red[3] + by[0];
}

extern "C" void kernel_launch(void* const* d_in, const int* in_sizes, int n_in,
                              void* d_out, int out_size, void* d_ws, size_t ws_size,
                              hipStream_t stream) {
    const float* x      = (const float*)d_in[0];
    const float* hidden = (const float*)d_in[1];
    const float* cell   = (const float*)d_in[2];
    const float* Wx[4]  = { (const float*)d_in[3], (const float*)d_in[4],
                            (const float*)d_in[5], (const float*)d_in[6] };
    const float* bx[4]  = { (const float*)d_in[7], (const float*)d_in[8],
                            (const float*)d_in[9], (const float*)d_in[10] };
    const float* Wh[4]  = { (const float*)d_in[11], (const float*)d_in[12],
                            (const float*)d_in[13], (const float*)d_in[14] };
    const float* Wy     = (const float*)d_in[15];
    const float* by     = (const float*)d_in[16];
    float* y = (float*)d_out;

    // ws layout (~208 MiB):
    //   A  bf16 [4096][5120]   : 40 MiB
    //   Wb bf16 [4096][5120]   : 40 MiB (reused per gate; stream-serialized)
    //   P  bf16 [4][4096][4096]: 128 MiB
    unsigned short* Ab = (unsigned short*)d_ws;
    unsigned short* Wb = Ab + (size_t)B_ * K_;
    unsigned short* Pg[4];
    {
        unsigned short* p0 = Wb + (size_t)H_ * K_;
        for (int g = 0; g < 4; ++g) Pg[g] = p0 + (size_t)g * B_ * H_;
    }

    const int cvt_grid = (B_ * (K_ / 4)) / 256;   // 20480, exact
    cvt_cat<<<cvt_grid, 256, 0, stream>>>(x, hidden, Ab);

    for (int g = 0; g < 4; ++g) {
        cvt_cat<<<cvt_grid, 256, 0, stream>>>(Wx[g], Wh[g], Wb);
        gemm_gate8<<<256, 512, 0, stream>>>(Ab, Wb, bx[g], Pg[g]);
    }

    gates_gemv<<<B_, 256, 0, stream>>>(Pg[0], Pg[1], Pg[2], Pg[3], cell, Wy, by, y);
}

// Round 4
// 741.779 us; speedup vs baseline: 1.4300x; 1.0309x over previous
//
#include <hip/hip_runtime.h>
#include <stdint.h>

// LSTM step: B=4096, IN=1024, H=4096. bf16-MFMA GEMMs with fp32 accumulate.
// GEMM = 256x256 tile, BK=64, 8 waves, m201-style 8-phase/2-K-tile pipeline:
// per phase {4-8-12 ds_read | 1 half-tile stage | barrier | lgkm0 | 16 MFMA},
// counted vmcnt once per K-tile (T3+T4), LDS XOR-swizzle (T2), setprio (T5),
// XCD-bijective block swizzle (T1).
#define IN_ 1024
#define H_  4096
#define B_  4096
#define K_  5120   // IN_ + H_ (K-concat of x|hidden and Wx|Wh)
#define NT_ 80     // K_ / 64 K-tiles

typedef short bf16x8 __attribute__((ext_vector_type(8)));
typedef float f32x4  __attribute__((ext_vector_type(4)));

__device__ __forceinline__ unsigned short f2bf(float x) {
    union { float f; uint32_t u; } v; v.f = x;
    return (unsigned short)((v.u + 0x7FFFu + ((v.u >> 16) & 1u)) >> 16);  // RNE
}
__device__ __forceinline__ float bf2f(uint32_t u16) {
    union { uint32_t u; float f; } v; v.u = u16 << 16; return v.f;
}

// Build bf16 [rows][5120] = concat(s1 [rows][1024], s2 [rows][4096]), RNE.
__global__ __launch_bounds__(256) void cvt_cat(
    const float* __restrict__ s1, const float* __restrict__ s2,
    unsigned short* __restrict__ dst)
{
    int idx = blockIdx.x * 256 + threadIdx.x;       // one float4 per thread
    int r = idx / (K_ / 4);
    int c = (idx % (K_ / 4)) * 4;
    float4 v;
    if (c < IN_) v = *(const float4*)(s1 + (size_t)r * IN_ + c);
    else         v = *(const float4*)(s2 + (size_t)r * H_ + (c - IN_));
    ushort4 o = { f2bf(v.x), f2bf(v.y), f2bf(v.z), f2bf(v.w) };
    *(ushort4*)(dst + (size_t)r * K_ + c) = o;
}

// LDS swizzle: within a [256][32]-bf16 sub-tile (64 B rows), XOR byte-col
// bits 4-5 with row bits 1-2. Measured conflict-free (round-2: SQ_LDS_BANK_CONFLICT=0).
__device__ __forceinline__ int swz(int row) { return ((row >> 1) & 3) << 4; }

// NT GEMM: P[m][n] = bf16( sum_k A[m][k]*W[n][k] + bias[n] )
// A [4096][5120] bf16, W [4096][5120] bf16, P [4096][4096] bf16.
__global__ __launch_bounds__(512, 2) void gemm_gate8(
    const unsigned short* __restrict__ A,
    const unsigned short* __restrict__ W,
    const float* __restrict__ bias,
    unsigned short* __restrict__ P)
{
    // 128 KiB: buf(2) x { A_k0 | A_k1 | B_k0 | B_k1 }, each [256][32] bf16 (16 KiB)
    __shared__ __align__(16) char ldsb[131072];

    const int tid  = threadIdx.x;
    const int wid  = tid >> 6;
    const int lane = tid & 63;

    // XCD-bijective block swizzle: 256 blocks, 8 XCDs, 32 blocks/XCD chunk.
    const int wg = (blockIdx.x & 7) * 32 + (blockIdx.x >> 3);
    const int mt = wg & 15, nt = wg >> 4;
    const int bm = mt * 256, bn = nt * 256;

    const int wm = wid >> 2;   // 0..1 -> wave M-half (128 rows)
    const int wn = wid & 3;    // 0..3 -> wave N-quarter (64 cols)

    const int l15 = lane & 15;
    const int c0  = (lane >> 4) << 4;   // fragment k-slot byte offset (0/16/32/48)

    // staging coords: thread owns 16B slots q0 = wid*64+lane and q0+512 of each
    // 16 KiB sub-tile; LDS write is linear, global SOURCE column pre-swizzled.
    const int q0  = wid * 64 + lane;
    const int r0  = q0 >> 2;                       // row 0..127
    const int cb0 = ((q0 & 3) << 4) ^ swz(r0);     // logical col byte
    const int r1  = r0 + 128;                      // row 128..255 (slot q0+512)
    const int cb1 = ((q0 & 3) << 4) ^ swz(r1);

    f32x4 acc[8][4];
#pragma unroll
    for (int i = 0; i < 8; ++i)
#pragma unroll
        for (int j = 0; j < 4; ++j) acc[i][j] = (f32x4){0.f, 0.f, 0.f, 0.f};

    // stage one sub-tile (2 x global_load_lds width-16 per thread)
    auto stage = [&](int isB, int ksel, int tau) {
        if (tau >= NT_) tau = NT_ - 2 + (tau & 1);  // tail clamp, parity-preserving
        const int kbase = tau * 64 + ksel * 32;
        const int chunk = (tau & 1) * 65536 + isB * 32768 + ksel * 16384;
        const unsigned short* src = isB ? W : A;
        const int gb = isB ? bn : bm;
        __builtin_amdgcn_global_load_lds(
            (const __attribute__((address_space(1))) void*)(src + (size_t)(gb + r0) * K_ + kbase + (cb0 >> 1)),
            (__attribute__((address_space(3))) void*)(ldsb + chunk + wid * 1024), 16, 0, 0);
        __builtin_amdgcn_global_load_lds(
            (const __attribute__((address_space(1))) void*)(src + (size_t)(gb + r1) * K_ + kbase + (cb1 >> 1)),
            (__attribute__((address_space(3))) void*)(ldsb + chunk + 8192 + wid * 1024), 16, 0, 0);
    };

    // prologue: buf0 <- tile0 (all 4 sub-tiles), buf1.B <- tile1.
    // vmcnt(4): tile0's 8 loads landed; buf1.B pair may stay in flight.
    stage(0, 0, 0); stage(0, 1, 0); stage(1, 0, 0); stage(1, 1, 0);
    stage(1, 0, 1); stage(1, 1, 1);
    asm volatile("s_waitcnt vmcnt(4)" ::: "memory");
    __builtin_amdgcn_s_barrier();

    for (int i = 0; i < NT_ / 2; ++i) {
        const int T0 = 2 * i;
#pragma unroll
        for (int half = 0; half < 2; ++half) {      // half 0: buf0/tile T0; half 1: buf1/tile T0+1
            const char* base  = ldsb + half * 65536;
            const char* Abase = base;               // A_k0 @0, A_k1 @16384
            const char* Bbase = base + 32768;       // B_k0, B_k1

            bf16x8 b[2][4];                          // live across the 4 quadrant phases
#pragma unroll
            for (int q = 0; q < 4; ++q) {
                // ds_reads: A-quadrant q (4), plus all B (8) in the first phase
                bf16x8 a[2][2];
#pragma unroll
                for (int kh = 0; kh < 2; ++kh)
#pragma unroll
                    for (int mi = 0; mi < 2; ++mi) {
                        const int row = wm * 128 + q * 32 + mi * 16 + l15;
                        a[kh][mi] = *(const bf16x8*)(Abase + kh * 16384 + row * 64 + (c0 ^ swz(row)));
                    }
                if (q == 0) {
#pragma unroll
                    for (int kh = 0; kh < 2; ++kh)
#pragma unroll
                        for (int ni = 0; ni < 4; ++ni) {
                            const int row = wn * 64 + ni * 16 + l15;
                            b[kh][ni] = *(const bf16x8*)(Bbase + kh * 16384 + row * 64 + (c0 ^ swz(row)));
                        }
                }

                // stage exactly 1 sub-tile per phase (dead-slot ledger):
                //  ph0: buf1.A_k0<-T0+1  ph1: buf1.A_k1<-T0+1   (buf1.A dead since prev ph7)
                //  ph2: buf0.B_k0<-T0+2  ph3: buf0.B_k1<-T0+2   (buf0.B dead after ph0)
                //  ph4: buf0.A_k0<-T0+2  ph5: buf0.A_k1<-T0+2   (buf0.A dead after ph3)
                //  ph6: buf1.B_k0<-T0+3  ph7: buf1.B_k1<-T0+3   (buf1.B dead after ph4)
                if (half == 0) {
                    if      (q == 0) stage(0, 0, T0 + 1);
                    else if (q == 1) stage(0, 1, T0 + 1);
                    else if (q == 2) stage(1, 0, T0 + 2);
                    else             stage(1, 1, T0 + 2);
                } else {
                    if      (q == 0) stage(0, 0, T0 + 2);
                    else if (q == 1) stage(0, 1, T0 + 2);
                    else if (q == 2) stage(1, 0, T0 + 3);
                    else             stage(1, 1, T0 + 3);
                }

                if (q == 0) asm volatile("s_waitcnt lgkmcnt(8)" ::: "memory");
                // counted vmcnt once per K-tile: allow newest 2 stages (4 loads)
                // in flight; forces the tile read next phase fully landed.
                if (q == 3) asm volatile("s_waitcnt vmcnt(4)" ::: "memory");
                __builtin_amdgcn_s_barrier();
                asm volatile("s_waitcnt lgkmcnt(0)" ::: "memory");
                __builtin_amdgcn_sched_barrier(0);   // rule #18: pin MFMA below the wait
                __builtin_amdgcn_s_setprio(1);
#pragma unroll
                for (int kh = 0; kh < 2; ++kh)
#pragma unroll
                    for (int mi = 0; mi < 2; ++mi)
#pragma unroll
                        for (int ni = 0; ni < 4; ++ni)
                            acc[q * 2 + mi][ni] = __builtin_amdgcn_mfma_f32_16x16x32_bf16(
                                a[kh][mi], b[kh][ni], acc[q * 2 + mi][ni], 0, 0, 0);
                __builtin_amdgcn_s_setprio(0);
                __builtin_amdgcn_s_barrier();
            }
        }
    }

    // epilogue: C/D layout col=lane&15, row=(lane>>4)*4+reg  [m89-verified]
#pragma unroll
    for (int ni = 0; ni < 4; ++ni) {
        const int col = bn + wn * 64 + ni * 16 + l15;
        const float bv = bias[col];
#pragma unroll
        for (int mi = 0; mi < 8; ++mi) {
            const int row0 = bm + wm * 128 + mi * 16 + (lane >> 4) * 4;
#pragma unroll
            for (int r = 0; r < 4; ++r)
                P[(size_t)(row0 + r) * H_ + col] = f2bf(acc[mi][ni][r] + bv);
        }
    }
}

// Fused gate elementwise + output GEMV. One block per batch row.
__global__ __launch_bounds__(256) void gates_gemv(
    const unsigned short* __restrict__ Pi, const unsigned short* __restrict__ Pf,
    const unsigned short* __restrict__ Po, const unsigned short* __restrict__ Pc,
    const float* __restrict__ cell, const float* __restrict__ Wy,
    const float* __restrict__ by, float* __restrict__ y)
{
    const int b = blockIdx.x;
    const int t = threadIdx.x;
    const size_t base = (size_t)b * H_;
    float part = 0.f;

#pragma unroll
    for (int j = 0; j < 4; ++j) {
        const int h = j * 1024 + t * 4;
        const uint2 ri = *(const uint2*)(Pi + base + h);
        const uint2 rf = *(const uint2*)(Pf + base + h);
        const uint2 ro = *(const uint2*)(Po + base + h);
        const uint2 rc = *(const uint2*)(Pc + base + h);
        const float4 cv = *(const float4*)(cell + base + h);
        const float4 wv = *(const float4*)(Wy + h);

        const uint32_t zi[4] = { ri.x & 0xffffu, ri.x >> 16, ri.y & 0xffffu, ri.y >> 16 };
        const uint32_t zf[4] = { rf.x & 0xffffu, rf.x >> 16, rf.y & 0xffffu, rf.y >> 16 };
        const uint32_t zo[4] = { ro.x & 0xffffu, ro.x >> 16, ro.y & 0xffffu, ro.y >> 16 };
        const uint32_t zc[4] = { rc.x & 0xffffu, rc.x >> 16, rc.y & 0xffffu, rc.y >> 16 };
        const float cc[4] = { cv.x, cv.y, cv.z, cv.w };
        const float ww[4] = { wv.x, wv.y, wv.z, wv.w };
#pragma unroll
        for (int e = 0; e < 4; ++e) {
            const float ig = 1.f / (1.f + __expf(-bf2f(zi[e])));
            const float fg = 1.f / (1.f + __expf(-bf2f(zf[e])));
            const float og = 1.f / (1.f + __expf(-bf2f(zo[e])));
            const float ct = tanhf(bf2f(zc[e]));
            const float cn = fg * cc[e] + ig * ct;
            const float hn = og * tanhf(cn);
            part += hn * ww[e];
        }
    }

    // block reduce (deterministic, no atomics)
#pragma unroll
    for (int off = 32; off > 0; off >>= 1) part += __shfl_down(part, off, 64);
    __shared__ float red[4];
    if ((t & 63) == 0) red[t >> 6] = part;
    __syncthreads();
    if (t == 0) y[b] = red[0] + red[1] + red[2] + red[3] + by[0];
}

extern "C" void kernel_launch(void* const* d_in, const int* in_sizes, int n_in,
                              void* d_out, int out_size, void* d_ws, size_t ws_size,
                              hipStream_t stream) {
    const float* x      = (const float*)d_in[0];
    const float* hidden = (const float*)d_in[1];
    const float* cell   = (const float*)d_in[2];
    const float* Wx[4]  = { (const float*)d_in[3], (const float*)d_in[4],
                            (const float*)d_in[5], (const float*)d_in[6] };
    const float* bx[4]  = { (const float*)d_in[7], (const float*)d_in[8],
                            (const float*)d_in[9], (const float*)d_in[10] };
    const float* Wh[4]  = { (const float*)d_in[11], (const float*)d_in[12],
                            (const float*)d_in[13], (const float*)d_in[14] };
    const float* Wy     = (const float*)d_in[15];
    const float* by     = (const float*)d_in[16];
    float* y = (float*)d_out;

    // ws layout (~208 MiB):
    //   A  bf16 [4096][5120]   : 40 MiB
    //   Wb bf16 [4096][5120]   : 40 MiB (reused per gate; stream-serialized)
    //   P  bf16 [4][4096][4096]: 128 MiB
    unsigned short* Ab = (unsigned short*)d_ws;
    unsigned short* Wb = Ab + (size_t)B_ * K_;
    unsigned short* Pg[4];
    {
        unsigned short* p0 = Wb + (size_t)H_ * K_;
        for (int g = 0; g < 4; ++g) Pg[g] = p0 + (size_t)g * B_ * H_;
    }

    const int cvt_grid = (B_ * (K_ / 4)) / 256;   // 20480, exact
    cvt_cat<<<cvt_grid, 256, 0, stream>>>(x, hidden, Ab);

    for (int g = 0; g < 4; ++g) {
        cvt_cat<<<cvt_grid, 256, 0, stream>>>(Wx[g], Wh[g], Wb);
        gemm_gate8<<<256, 512, 0, stream>>>(Ab, Wb, bx[g], Pg[g]);
    }

    gates_gemv<<<B_, 256, 0, stream>>>(Pg[0], Pg[1], Pg[2], Pg[3], cell, Wy, by, y);
}

// Round 5
// 705.526 us; speedup vs baseline: 1.5034x; 1.0514x over previous
//
#include <hip/hip_runtime.h>
#include <stdint.h>

// LSTM step: B=4096, IN=1024, H=4096. bf16-MFMA GEMMs with fp32 accumulate.
// GEMM = 256x256 tile, BK=64, 8 waves, 8-phase/2-K-tile pipeline with ONE
// barrier per phase, kh-split MFMA clusters (compiler-counted lgkm waits),
// counted vmcnt (T3+T4), LDS XOR-swizzle (T2), setprio (T5), XCD swizzle (T1).
#define IN_ 1024
#define H_  4096
#define B_  4096
#define K_  5120   // IN_ + H_ (K-concat of x|hidden and Wx|Wh)
#define NT_ 80     // K_ / 64 K-tiles

typedef short bf16x8 __attribute__((ext_vector_type(8)));
typedef float f32x4  __attribute__((ext_vector_type(4)));

__device__ __forceinline__ unsigned short f2bf(float x) {
    union { float f; uint32_t u; } v; v.f = x;
    return (unsigned short)((v.u + 0x7FFFu + ((v.u >> 16) & 1u)) >> 16);  // RNE
}
__device__ __forceinline__ float bf2f(uint32_t u16) {
    union { uint32_t u; float f; } v; v.u = u16 << 16; return v.f;
}

// Build bf16 [rows][5120] = concat(s1 [rows][1024], s2 [rows][4096]), RNE.
__global__ __launch_bounds__(256) void cvt_cat(
    const float* __restrict__ s1, const float* __restrict__ s2,
    unsigned short* __restrict__ dst)
{
    int idx = blockIdx.x * 256 + threadIdx.x;       // one float4 per thread
    int r = idx / (K_ / 4);
    int c = (idx % (K_ / 4)) * 4;
    float4 v;
    if (c < IN_) v = *(const float4*)(s1 + (size_t)r * IN_ + c);
    else         v = *(const float4*)(s2 + (size_t)r * H_ + (c - IN_));
    ushort4 o = { f2bf(v.x), f2bf(v.y), f2bf(v.z), f2bf(v.w) };
    *(ushort4*)(dst + (size_t)r * K_ + c) = o;
}

// LDS swizzle: within a [256][32]-bf16 sub-tile (64 B rows), XOR byte-col
// bits 4-5 with row bits 1-2. Measured conflict-free (SQ_LDS_BANK_CONFLICT=0).
__device__ __forceinline__ int swz(int row) { return ((row >> 1) & 3) << 4; }

// NT GEMM: P[m][n] = bf16( sum_k A[m][k]*W[n][k] + bias[n] )
// A [4096][5120] bf16, W [4096][5120] bf16, P [4096][4096] bf16.
__global__ __launch_bounds__(512, 2) void gemm_gate8(
    const unsigned short* __restrict__ A,
    const unsigned short* __restrict__ W,
    const float* __restrict__ bias,
    unsigned short* __restrict__ P)
{
    // 128 KiB: buf(2) x { A_k0 | A_k1 | B_k0 | B_k1 }, each [256][32] bf16 (16 KiB)
    __shared__ __align__(16) char ldsb[131072];

    const int tid  = threadIdx.x;
    const int wid  = tid >> 6;
    const int lane = tid & 63;

    // XCD-bijective block swizzle: 256 blocks, 8 XCDs, 32 blocks/XCD chunk.
    const int wg = (blockIdx.x & 7) * 32 + (blockIdx.x >> 3);
    const int mt = wg & 15, nt = wg >> 4;
    const int bm = mt * 256, bn = nt * 256;

    const int wm = wid >> 2;   // 0..1 -> wave M-half (128 rows)
    const int wn = wid & 3;    // 0..3 -> wave N-quarter (64 cols)

    const int l15 = lane & 15;
    const int c0  = (lane >> 4) << 4;   // fragment k-slot byte offset (0/16/32/48)

    // staging coords: thread owns 16B slots q0 = wid*64+lane and q0+512 of each
    // 16 KiB sub-tile; LDS write is linear, global SOURCE column pre-swizzled.
    const int q0  = wid * 64 + lane;
    const int r0  = q0 >> 2;                       // row 0..127
    const int cb0 = ((q0 & 3) << 4) ^ swz(r0);     // logical col byte
    const int r1  = r0 + 128;                      // row 128..255 (slot q0+512)
    const int cb1 = ((q0 & 3) << 4) ^ swz(r1);

    f32x4 acc[8][4];
#pragma unroll
    for (int i = 0; i < 8; ++i)
#pragma unroll
        for (int j = 0; j < 4; ++j) acc[i][j] = (f32x4){0.f, 0.f, 0.f, 0.f};

    // stage one sub-tile (2 x global_load_lds width-16 per thread)
    auto stage = [&](int isB, int ksel, int tau) {
        if (tau >= NT_) tau = NT_ - 2 + (tau & 1);  // tail clamp, parity-preserving
        const int kbase = tau * 64 + ksel * 32;
        const int chunk = (tau & 1) * 65536 + isB * 32768 + ksel * 16384;
        const unsigned short* src = isB ? W : A;
        const int gb = isB ? bn : bm;
        __builtin_amdgcn_global_load_lds(
            (const __attribute__((address_space(1))) void*)(src + (size_t)(gb + r0) * K_ + kbase + (cb0 >> 1)),
            (__attribute__((address_space(3))) void*)(ldsb + chunk + wid * 1024), 16, 0, 0);
        __builtin_amdgcn_global_load_lds(
            (const __attribute__((address_space(1))) void*)(src + (size_t)(gb + r1) * K_ + kbase + (cb1 >> 1)),
            (__attribute__((address_space(3))) void*)(ldsb + chunk + 8192 + wid * 1024), 16, 0, 0);
    };

    // prologue: buf0 <- tile0 (A+B), buf1.B <- tile1.
    // vmcnt(4): tile0's 8 loads landed; buf1.B pair (4 loads) may stay in flight.
    stage(0, 0, 0); stage(0, 1, 0); stage(1, 0, 0); stage(1, 1, 0);
    stage(1, 0, 1); stage(1, 1, 1);
    asm volatile("s_waitcnt vmcnt(4)" ::: "memory");
    __builtin_amdgcn_s_barrier();

    for (int i = 0; i < NT_ / 2; ++i) {
        const int T0 = 2 * i;
        bf16x8 b[2][4];     // B fragments, refreshed at phases 0 and 4
#pragma unroll
        for (int k = 0; k < 8; ++k) {
            const int half = k >> 2;            // buf index (T0 even)
            const int q    = k & 3;             // C-quadrant
            const char* Abase = ldsb + half * 65536;
            const char* Bbase = Abase + 32768;

            // [R] reads, kh0 group first so the compiler's counted lgkm wait
            // lets MFMA-kh0 start while kh1 reads are still in flight.
            bf16x8 a0[2], a1[2];
            if (q == 0) {
#pragma unroll
                for (int ni = 0; ni < 4; ++ni) {
                    const int row = wn * 64 + ni * 16 + l15;
                    b[0][ni] = *(const bf16x8*)(Bbase + row * 64 + (c0 ^ swz(row)));
                }
            }
#pragma unroll
            for (int mi = 0; mi < 2; ++mi) {
                const int row = wm * 128 + q * 32 + mi * 16 + l15;
                a0[mi] = *(const bf16x8*)(Abase + row * 64 + (c0 ^ swz(row)));
            }
            if (q == 0) {
#pragma unroll
                for (int ni = 0; ni < 4; ++ni) {
                    const int row = wn * 64 + ni * 16 + l15;
                    b[1][ni] = *(const bf16x8*)(Bbase + 16384 + row * 64 + (c0 ^ swz(row)));
                }
            }
#pragma unroll
            for (int mi = 0; mi < 2; ++mi) {
                const int row = wm * 128 + q * 32 + mi * 16 + l15;
                a1[mi] = *(const bf16x8*)(Abase + 16384 + row * 64 + (c0 ^ swz(row)));
            }

            // [V] collective landing guarantee for the NEXT 4 phases' reads:
            // vmcnt(2) allows only this phase's not-yet-issued... i.e. the
            // newest in-flight stage (previous phase's) to remain outstanding.
            if (q == 3) asm volatile("s_waitcnt vmcnt(2)" ::: "memory");
            // [BAR] one barrier per phase
            __builtin_amdgcn_s_barrier();

            // [S] stage exactly 1 sub-tile per phase (dead-slot ledger):
            //  ph0: buf1.A_k0<-T0+1  ph1: buf1.A_k1<-T0+1  (buf1.A last read ph7 prev)
            //  ph2: buf0.B_k0<-T0+2  ph3: buf0.B_k1<-T0+2  (buf0.B last read ph0)
            //  ph4: buf0.A_k0<-T0+2  ph5: buf0.A_k1<-T0+2  (buf0.A last read ph3)
            //  ph6: buf1.B_k0<-T0+3  ph7: buf1.B_k1<-T0+3  (buf1.B last read ph4)
            if      (k == 0) stage(0, 0, T0 + 1);
            else if (k == 1) stage(0, 1, T0 + 1);
            else if (k == 2) stage(1, 0, T0 + 2);
            else if (k == 3) stage(1, 1, T0 + 2);
            else if (k == 4) stage(0, 0, T0 + 2);
            else if (k == 5) stage(0, 1, T0 + 2);
            else if (k == 6) stage(1, 0, T0 + 3);
            else             stage(1, 1, T0 + 3);
            __builtin_amdgcn_sched_barrier(0);   // pin MFMA below barrier+stage

            __builtin_amdgcn_s_setprio(1);
#pragma unroll
            for (int mi = 0; mi < 2; ++mi)        // kh0 cluster (8 MFMA)
#pragma unroll
                for (int ni = 0; ni < 4; ++ni)
                    acc[q * 2 + mi][ni] = __builtin_amdgcn_mfma_f32_16x16x32_bf16(
                        a0[mi], b[0][ni], acc[q * 2 + mi][ni], 0, 0, 0);
#pragma unroll
            for (int mi = 0; mi < 2; ++mi)        // kh1 cluster (8 MFMA)
#pragma unroll
                for (int ni = 0; ni < 4; ++ni)
                    acc[q * 2 + mi][ni] = __builtin_amdgcn_mfma_f32_16x16x32_bf16(
                        a1[mi], b[1][ni], acc[q * 2 + mi][ni], 0, 0, 0);
            __builtin_amdgcn_s_setprio(0);
        }
    }

    // epilogue: C/D layout col=lane&15, row=(lane>>4)*4+reg  [m89-verified]
#pragma unroll
    for (int ni = 0; ni < 4; ++ni) {
        const int col = bn + wn * 64 + ni * 16 + l15;
        const float bv = bias[col];
#pragma unroll
        for (int mi = 0; mi < 8; ++mi) {
            const int row0 = bm + wm * 128 + mi * 16 + (lane >> 4) * 4;
#pragma unroll
            for (int r = 0; r < 4; ++r)
                P[(size_t)(row0 + r) * H_ + col] = f2bf(acc[mi][ni][r] + bv);
        }
    }
}

// Fused gate elementwise + output GEMV. One block per batch row.
__global__ __launch_bounds__(256) void gates_gemv(
    const unsigned short* __restrict__ Pi, const unsigned short* __restrict__ Pf,
    const unsigned short* __restrict__ Po, const unsigned short* __restrict__ Pc,
    const float* __restrict__ cell, const float* __restrict__ Wy,
    const float* __restrict__ by, float* __restrict__ y)
{
    const int b = blockIdx.x;
    const int t = threadIdx.x;
    const size_t base = (size_t)b * H_;
    float part = 0.f;

#pragma unroll
    for (int j = 0; j < 4; ++j) {
        const int h = j * 1024 + t * 4;
        const uint2 ri = *(const uint2*)(Pi + base + h);
        const uint2 rf = *(const uint2*)(Pf + base + h);
        const uint2 ro = *(const uint2*)(Po + base + h);
        const uint2 rc = *(const uint2*)(Pc + base + h);
        const float4 cv = *(const float4*)(cell + base + h);
        const float4 wv = *(const float4*)(Wy + h);

        const uint32_t zi[4] = { ri.x & 0xffffu, ri.x >> 16, ri.y & 0xffffu, ri.y >> 16 };
        const uint32_t zf[4] = { rf.x & 0xffffu, rf.x >> 16, rf.y & 0xffffu, rf.y >> 16 };
        const uint32_t zo[4] = { ro.x & 0xffffu, ro.x >> 16, ro.y & 0xffffu, ro.y >> 16 };
        const uint32_t zc[4] = { rc.x & 0xffffu, rc.x >> 16, rc.y & 0xffffu, rc.y >> 16 };
        const float cc[4] = { cv.x, cv.y, cv.z, cv.w };
        const float ww[4] = { wv.x, wv.y, wv.z, wv.w };
#pragma unroll
        for (int e = 0; e < 4; ++e) {
            const float ig = 1.f / (1.f + __expf(-bf2f(zi[e])));
            const float fg = 1.f / (1.f + __expf(-bf2f(zf[e])));
            const float og = 1.f / (1.f + __expf(-bf2f(zo[e])));
            const float ct = tanhf(bf2f(zc[e]));
            const float cn = fg * cc[e] + ig * ct;
            const float hn = og * tanhf(cn);
            part += hn * ww[e];
        }
    }

    // block reduce (deterministic, no atomics)
#pragma unroll
    for (int off = 32; off > 0; off >>= 1) part += __shfl_down(part, off, 64);
    __shared__ float red[4];
    if ((t & 63) == 0) red[t >> 6] = part;
    __syncthreads();
    if (t == 0) y[b] = red[0] + red[1] + red[2] + red[3] + by[0];
}

extern "C" void kernel_launch(void* const* d_in, const int* in_sizes, int n_in,
                              void* d_out, int out_size, void* d_ws, size_t ws_size,
                              hipStream_t stream) {
    const float* x      = (const float*)d_in[0];
    const float* hidden = (const float*)d_in[1];
    const float* cell   = (const float*)d_in[2];
    const float* Wx[4]  = { (const float*)d_in[3], (const float*)d_in[4],
                            (const float*)d_in[5], (const float*)d_in[6] };
    const float* bx[4]  = { (const float*)d_in[7], (const float*)d_in[8],
                            (const float*)d_in[9], (const float*)d_in[10] };
    const float* Wh[4]  = { (const float*)d_in[11], (const float*)d_in[12],
                            (const float*)d_in[13], (const float*)d_in[14] };
    const float* Wy     = (const float*)d_in[15];
    const float* by     = (const float*)d_in[16];
    float* y = (float*)d_out;

    // ws layout (~208 MiB):
    //   A  bf16 [4096][5120]   : 40 MiB
    //   Wb bf16 [4096][5120]   : 40 MiB (reused per gate; stream-serialized)
    //   P  bf16 [4][4096][4096]: 128 MiB
    unsigned short* Ab = (unsigned short*)d_ws;
    unsigned short* Wb = Ab + (size_t)B_ * K_;
    unsigned short* Pg[4];
    {
        unsigned short* p0 = Wb + (size_t)H_ * K_;
        for (int g = 0; g < 4; ++g) Pg[g] = p0 + (size_t)g * B_ * H_;
    }

    const int cvt_grid = (B_ * (K_ / 4)) / 256;   // 20480, exact
    cvt_cat<<<cvt_grid, 256, 0, stream>>>(x, hidden, Ab);

    for (int g = 0; g < 4; ++g) {
        cvt_cat<<<cvt_grid, 256, 0, stream>>>(Wx[g], Wh[g], Wb);
        gemm_gate8<<<256, 512, 0, stream>>>(Ab, Wb, bx[g], Pg[g]);
    }

    gates_gemv<<<B_, 256, 0, stream>>>(Pg[0], Pg[1], Pg[2], Pg[3], cell, Wy, by, y);
}